// Round 3
// baseline (604.349 us; speedup 1.0000x reference)
//
#include <hip/hip_runtime.h>
#include <stdint.h>

// ---------------------------------------------------------------------------
// GAU forward on MI355X (gfx950), bf16 MFMA everywhere.
//   hid|qk = silu(x@[Wh|Wqk]+b) -> vT [2048][8192], gate [8192][2048],
//                                  q,k bf16 [8192][256] (cols 200..255 zero)
//   attn = relu(q@kT / 32)^2    bf16 (full [8192][8192] if ws allows, else 2 stripes)
//   out2 = (attn@v) * gate      bf16 [8192][2048]
//   y    = (out2@Wo + bo) * x   fp32 [8192][1024]
//
// R10: k_pv rework after R9 null (barrier removal didn't help; model says
// per-tile LDS-read burst and MFMA burst SERIALIZE under lockstep waves,
// 770+1242 ~= measured 2082 cyc/tile). Also: totals reconcile only if we
// are in the 2-stripe path, where the old 256x256 k_pv grid (128 blocks)
// left HALF the GPU idle for 2x222 us.
//   - Tile 128x256 (wave 64x64, acc[4][4]): stripe grid = 256 blocks =
//     1/CU (full machine); per-CU LDS traffic 96->64 KB/tile.
//   - Register double-buffer: at tile t, stage(t+3) + ds_read frags(t+1)
//     into the NEXT reg set, then MFMA tile t from CURRENT set -> LDS
//     burst overlaps MFMA burst (no dependency).
//   - Ring-4 slots (24 KB each, 96 KB LDS), per-tile vmcnt(3) (3 gloads/
//     wave/tile): slot t+1 resident before its frags are read at tile t;
//     loads get ~1.9 tiles (~1400 cyc) of flight.
// k_hidqk / k_attn / k_final unchanged from R9.
// ---------------------------------------------------------------------------

typedef __bf16 bf16x8 __attribute__((ext_vector_type(8)));
typedef float f32x4 __attribute__((ext_vector_type(4)));

__device__ __forceinline__ uint16_t f2bf(float f) {
  uint32_t u = __builtin_bit_cast(uint32_t, f);
  u += 0x7fffu + ((u >> 16) & 1u);   // RNE; inputs are finite
  return (uint16_t)(u >> 16);
}
__device__ __forceinline__ float silu_f(float s) {
  return s / (1.f + __expf(-s));
}

__device__ __forceinline__ void gload16(const void* g, void* l) {
  __builtin_amdgcn_global_load_lds(
      (__attribute__((address_space(1))) void*)const_cast<void*>(g),
      (__attribute__((address_space(3))) void*)l, 16, 0, 0);
}

// ---------------- elementwise prep ----------------

__global__ void cast_to_bf16(const float* __restrict__ in, uint16_t* __restrict__ out, int n4) {
  int i = blockIdx.x * blockDim.x + threadIdx.x;
  if (i < n4) {
    float4 f = ((const float4*)in)[i];
    ushort4 o;
    o.x = f2bf(f.x); o.y = f2bf(f.y); o.z = f2bf(f.z); o.w = f2bf(f.w);
    ((ushort4*)out)[i] = o;
  }
}

// out[c][r] = (c < C) ? (bf16)in[r][c] : 0   ; out is [Cp][R]
__global__ void transpose_cast_pad(const float* __restrict__ in, uint16_t* __restrict__ out,
                                   int R, int C, int Cp) {
  __shared__ float tile[32][33];
  int cb = blockIdx.x * 32;
  int rb = blockIdx.y * 32;
  int tx = threadIdx.x;
  int ty = threadIdx.y;
#pragma unroll
  for (int i = 0; i < 4; ++i) {
    int r = rb + ty + i * 8;
    int c = cb + tx;
    tile[ty + i * 8][tx] = (c < C) ? in[(size_t)r * C + c] : 0.f;
  }
  __syncthreads();
#pragma unroll
  for (int i = 0; i < 4; ++i) {
    int c = cb + ty + i * 8;
    if (c < Cp) out[(size_t)c * R + rb + tx] = f2bf(tile[tx][ty + i * 8]);
  }
}

// ---------------- params ----------------

struct EpiParams {
  const float* bias;
  const float* bias2;
  const float* g0;
  const float* b0;
  const float* g1;
  const float* b1;
  const uint16_t* gate;
  const float* x;
  uint16_t* o16a;
  uint16_t* o16b;
  uint16_t* oq;
  uint16_t* ok;
  float* o32;
};

// ---------------------------------------------------------------------------
// Shared 128x128 ring-4 K-loop (4 waves, BK=32, 64 KB LDS, 2 blocks/CU).
// Requires in scope: SH (uint16_t[32768]), NT (pow2), wave, rdA, rdB,
// gA0,gA1,gB0,gB1 (swizzled-source stage pointers), acc[4][4].
// Slot s: A at s*8192, B at s*8192+4096. Stage tile t+3 during tile t;
// vmcnt(8) once per tile (2 tiles of loads stay in flight).
// ---------------------------------------------------------------------------
#define TILE128(T_, B_, BS_)                                                   \
  do {                                                                         \
    const uint16_t* base_ = SH + (B_) * 8192;                                  \
    const int kp_ = (((T_) + 3) & (NT - 1)) * 32;                              \
    uint16_t* sd_ = SH + (BS_) * 8192 + wave * 512;                            \
    gload16(gA0 + kp_, sd_);                                                   \
    gload16(gA1 + kp_, sd_ + 2048);                                            \
    gload16(gB0 + kp_, sd_ + 4096);                                            \
    gload16(gB1 + kp_, sd_ + 6144);                                            \
    bf16x8 a_[4], b_[4];                                                       \
    _Pragma("unroll") for (int j = 0; j < 4; ++j)                              \
        b_[j] = *(const bf16x8*)(base_ + rdB + j * 512);                       \
    _Pragma("unroll") for (int i = 0; i < 4; ++i)                              \
        a_[i] = *(const bf16x8*)(base_ + rdA + i * 512);                       \
    __builtin_amdgcn_s_setprio(1);                                             \
    _Pragma("unroll") for (int i = 0; i < 4; ++i)                              \
      _Pragma("unroll") for (int j = 0; j < 4; ++j)                            \
          acc[i][j] = __builtin_amdgcn_mfma_f32_16x16x32_bf16(                 \
              a_[i], b_[j], acc[i][j], 0, 0, 0);                               \
    __builtin_amdgcn_s_setprio(0);                                             \
    asm volatile("s_waitcnt vmcnt(8)" ::: "memory");                           \
    __builtin_amdgcn_sched_barrier(0);                                         \
    __builtin_amdgcn_s_barrier();                                              \
    __builtin_amdgcn_sched_barrier(0);                                         \
  } while (0)

#define RING_LOOP128()                                                         \
  do {                                                                         \
    _Pragma("unroll") for (int s_ = 0; s_ < 3; ++s_) {                         \
      uint16_t* d_ = SH + s_ * 8192 + wave * 512;                              \
      gload16(gA0 + s_ * 32, d_);                                              \
      gload16(gA1 + s_ * 32, d_ + 2048);                                       \
      gload16(gB0 + s_ * 32, d_ + 4096);                                       \
      gload16(gB1 + s_ * 32, d_ + 6144);                                       \
    }                                                                          \
    asm volatile("s_waitcnt vmcnt(8)" ::: "memory");                           \
    __builtin_amdgcn_sched_barrier(0);                                         \
    __builtin_amdgcn_s_barrier();                                              \
    __builtin_amdgcn_sched_barrier(0);                                         \
    for (int t0_ = 0; t0_ < NT; t0_ += 4) {                                    \
      TILE128(t0_ + 0, 0, 3);                                                  \
      TILE128(t0_ + 1, 1, 0);                                                  \
      TILE128(t0_ + 2, 2, 1);                                                  \
      TILE128(t0_ + 3, 3, 2);                                                  \
    }                                                                          \
    asm volatile("s_waitcnt vmcnt(0)" ::: "memory");                           \
    __builtin_amdgcn_sched_barrier(0);                                         \
    __syncthreads();                                                           \
  } while (0)

// ---------------------------------------------------------------------------
// k_hidqk: C = xb[8192,1024] @ [WhT;WqkT][4352,1024]^T, 128x128 tile.
// ---------------------------------------------------------------------------
__global__ __launch_bounds__(256, 2) void k_hidqk(
    const uint16_t* __restrict__ A, const uint16_t* __restrict__ Bt, EpiParams p) {
  __shared__ __align__(16) uint16_t SH[32768];   // 4 ring slots x (A|B), 64 KB

  const int tid = threadIdx.x;
  const int lane = tid & 63;
  const int wave = tid >> 6;
  const int wr = (wave >> 1) * 64;
  const int wc = (wave & 1) * 64;
  const int m0 = blockIdx.y * 128;
  const int n0 = blockIdx.x * 128;
  const int lda = 1024, ldb = 1024;
  const int NT = 32;   // K=1024

  f32x4 acc[4][4] = {};

  const int fr = lane & 15;
  const int rg = lane >> 4;
  const int swz = (rg ^ ((fr >> 1) & 3)) * 8;
  const int rdA = (wr + fr) * 32 + swz;
  const int rdB = 4096 + (wc + fr) * 32 + swz;

  const int srow = lane >> 2;
  const int sk = ((lane & 3) ^ ((lane >> 3) & 3)) * 8;
  const uint16_t* gA0 = A + (size_t)(m0 + wave * 16 + srow) * lda + sk;
  const uint16_t* gA1 = gA0 + (size_t)64 * lda;
  const uint16_t* gB0 = Bt + (size_t)(n0 + wave * 16 + srow) * ldb + sk;
  const uint16_t* gB1 = gB0 + (size_t)64 * ldb;

  RING_LOOP128();

  // C/D layout: col = lane&15, row = rg*4 + reg   [m89-verified]
  if (n0 < 2048) {
    // vT (transposed store). Arena [16 n-rows][64 m + pad] stride 72.
    uint16_t* ar = SH + wave * 2048;
    const int lrow = lane >> 3;
    const int mc = (lane & 7) * 8;
#pragma unroll
    for (int j = 0; j < 4; ++j) {
      const float bc = p.bias[n0 + wc + j * 16 + fr];
#pragma unroll
      for (int i = 0; i < 4; ++i)
#pragma unroll
        for (int r = 0; r < 4; ++r)
          ar[fr * 72 + i * 16 + rg * 4 + r] = f2bf(silu_f(acc[i][j][r] + bc));
#pragma unroll
      for (int rr = 0; rr < 2; ++rr) {
        bf16x8 v = *(const bf16x8*)(ar + (rr * 8 + lrow) * 72 + mc);
        *(bf16x8*)(p.o16a + (size_t)(n0 + wc + j * 16 + rr * 8 + lrow) * 8192 + m0 + wr + mc) = v;
      }
    }
  } else if (n0 < 4096) {
    // gate. Arena [16 m-rows][64 n + pad] stride 72.
    uint16_t* ar = SH + wave * 2048;
    const int lrow = lane >> 3;
    const int nc = (lane & 7) * 8;
    float bc[4];
#pragma unroll
    for (int j = 0; j < 4; ++j) bc[j] = p.bias[n0 + wc + j * 16 + fr];
#pragma unroll
    for (int i = 0; i < 4; ++i) {
#pragma unroll
      for (int j = 0; j < 4; ++j)
#pragma unroll
        for (int r = 0; r < 4; ++r)
          ar[(rg * 4 + r) * 72 + j * 16 + fr] = f2bf(silu_f(acc[i][j][r] + bc[j]));
#pragma unroll
      for (int rr = 0; rr < 2; ++rr) {
        bf16x8 v = *(const bf16x8*)(ar + (rr * 8 + lrow) * 72 + nc);
        *(bf16x8*)(p.o16b + (size_t)(m0 + wr + i * 16 + rr * 8 + lrow) * 2048 + (n0 - 2048) + wc + nc) = v;
      }
    }
  } else {
    // q,k: stride 256, cols 200..255 forced zero.
#pragma unroll
    for (int i = 0; i < 4; ++i) {
#pragma unroll
      for (int j = 0; j < 4; ++j) {
        const int row = m0 + wr + i * 16 + rg * 4;
        const int qc = n0 + wc + j * 16 + fr - 4096;   // 0..255
#pragma unroll
        for (int r = 0; r < 4; ++r) {
          float qv = 0.f, kv = 0.f;
          if (qc < 200) {
            float s = silu_f(acc[i][j][r] + p.bias2[qc]);
            qv = s * p.g0[qc] + p.b0[qc];
            kv = s * p.g1[qc] + p.b1[qc];
          }
          p.oq[(size_t)(row + r) * 256 + qc] = f2bf(qv);
          p.ok[(size_t)(row + r) * 256 + qc] = f2bf(kv);
        }
      }
    }
  }
}

// ---------------------------------------------------------------------------
// k_attn: attn = relu(q@kT/32)^2, K=256 (padded), 128x128 tile, ring-4.
// ---------------------------------------------------------------------------
__global__ __launch_bounds__(256, 2) void k_attn(
    const uint16_t* __restrict__ Q,
    const uint16_t* __restrict__ Kt,
    uint16_t* __restrict__ attn) {
  __shared__ __align__(16) uint16_t SH[32768];

  const int tid = threadIdx.x;
  const int lane = tid & 63;
  const int wave = tid >> 6;
  const int wr = (wave >> 1) * 64;
  const int wc = (wave & 1) * 64;
  const int m0 = blockIdx.y * 128;
  const int n0 = blockIdx.x * 128;
  const int lda = 256, ldb = 256;
  const int NT = 8;   // K=256

  f32x4 acc[4][4] = {};

  const int fr = lane & 15;
  const int rg = lane >> 4;
  const int swz = (rg ^ ((fr >> 1) & 3)) * 8;
  const int rdA = (wr + fr) * 32 + swz;
  const int rdB = 4096 + (wc + fr) * 32 + swz;

  const int srow = lane >> 2;
  const int sk = ((lane & 3) ^ ((lane >> 3) & 3)) * 8;
  const uint16_t* gA0 = Q + (size_t)(m0 + wave * 16 + srow) * lda + sk;
  const uint16_t* gA1 = gA0 + (size_t)64 * lda;
  const uint16_t* gB0 = Kt + (size_t)(n0 + wave * 16 + srow) * ldb + sk;
  const uint16_t* gB1 = gB0 + (size_t)64 * ldb;

  RING_LOOP128();

  // bounce epilogue: per i, wave-local [16 rows][64 cols] stride 72, dbuf
#pragma unroll
  for (int i = 0; i < 4; ++i) {
    uint16_t* sl = SH + wave * 4096 + (i & 1) * 2048;
#pragma unroll
    for (int j = 0; j < 4; ++j)
#pragma unroll
      for (int r = 0; r < 4; ++r) {
        float s = fmaxf(acc[i][j][r] * 0.03125f, 0.f);
        sl[(rg * 4 + r) * 72 + j * 16 + fr] = f2bf(s * s);
      }
    const int row = lane >> 2;
    const int c0 = (lane & 3) * 16;
    bf16x8 v0 = *(const bf16x8*)(sl + row * 72 + c0);
    bf16x8 v1 = *(const bf16x8*)(sl + row * 72 + c0 + 8);
    uint16_t* dst = attn + (size_t)(m0 + wr + i * 16 + row) * 8192 + (n0 + wc + c0);
    *(bf16x8*)(dst) = v0;
    *(bf16x8*)(dst + 8) = v1;
  }
}

// ---------------------------------------------------------------------------
// k_pv: out2 = (attn@v)*gate.  128(M) x 256(N) tile, BK=32, 512 thr, 8 waves
// (2Mx4N, wave 64x64, acc[4][4]). Ring-4 of 24 KB slots (96 KB LDS),
// register double-buffer: tile t stages slot t+3, ds_reads frags(t+1) into
// the NEXT reg set, MFMAs tile t from CURRENT set (LDS burst overlaps MFMA
// burst). vmcnt(3)/tile (3 gloads/wave/tile). 1 block/CU; stripe grid 256
// blocks fills the machine (fullM: 512, two rounds).
// ---------------------------------------------------------------------------
__global__ __launch_bounds__(512, 2) void k_pv(
    const uint16_t* __restrict__ A, int lda,
    const uint16_t* __restrict__ Bt, int ldb,
    int K, int nx, EpiParams p) {
  __shared__ __align__(16) uint16_t SH[49152];   // 4 x (A 8KB | B 16KB) = 96 KB

  const int id = blockIdx.x;
  const int bx = (id >> 3) % nx;                 // per-XCD A-panel reuse across bx
  const int by = (id & 7) + 8 * (id / (8 * nx));
  const int m0 = by * 128;
  const int n0 = bx * 256;

  const int tid = threadIdx.x;
  const int lane = tid & 63;
  const int wave = tid >> 6;
  const int wrM = (wave >> 2) * 64;    // wave M origin (0/64)
  const int wcN = (wave & 3) * 64;     // wave N origin (0/64/128/192)

  const int fr = lane & 15;
  const int rg = lane >> 4;
  const int swz = (rg ^ ((fr >> 1) & 3)) * 8;

  const int rdA = (wrM + fr) * 32 + swz;          // + slot*12288 + i*512
  const int rdB = 4096 + (wcN + fr) * 32 + swz;   // + slot*12288 + j*512

  // stage: wave w covers A rows [w*16,w*16+16) (1 gload), B rows
  // [w*32,w*32+32) (2 gloads). Linear LDS dest; inverse-swizzled global src.
  const int srow = lane >> 2;
  const int sk = ((lane & 3) ^ ((lane >> 3) & 3)) * 8;
  const uint16_t* gA0 = A + (size_t)(m0 + wave * 16 + srow) * lda + sk;
  const uint16_t* gB0 = Bt + (size_t)(n0 + wave * 32 + srow) * ldb + sk;
  const uint16_t* gB1 = gB0 + (size_t)16 * ldb;

  f32x4 acc[4][4] = {};
  const int NT = K >> 5;   // 256 K-tiles of 32

  // prologue: stage slots 0,1,2; vmcnt(3) -> slots 0,1 resident
  for (int s = 0; s < 3; ++s) {
    const int ko = s * 32;
    uint16_t* d = SH + s * 12288;
    gload16(gA0 + ko, d + wave * 512);
    gload16(gB0 + ko, d + 4096 + wave * 1024);
    gload16(gB1 + ko, d + 4096 + wave * 1024 + 512);
  }
  asm volatile("s_waitcnt vmcnt(3)" ::: "memory");
  __builtin_amdgcn_sched_barrier(0);
  __builtin_amdgcn_s_barrier();
  __builtin_amdgcn_sched_barrier(0);

  bf16x8 fa0[4], fb0[4], fa1[4], fb1[4];
#pragma unroll
  for (int j = 0; j < 4; ++j) fb0[j] = *(const bf16x8*)(SH + rdB + j * 512);
#pragma unroll
  for (int i = 0; i < 4; ++i) fa0[i] = *(const bf16x8*)(SH + rdA + i * 512);

  // Tile t: stage slot (t+3), read frags(t+1) from slot (t+1) into NEXT set,
  // MFMA CURRENT set, vmcnt(3) [completes slot t+2 -> slot t+2 resident for
  // frags read at tile t+1], barrier. Invariant: at tile t entry, slots
  // <= t+1 resident. Final iteration's frag read is wrapped garbage (dead).
#define PV_T(T_, RS_, WS_, CA_, CB_, NA_, NB_)                                 \
  do {                                                                         \
    const int kp_ = (((T_) + 3) & (NT - 1)) * 32;                              \
    uint16_t* sd_ = SH + (WS_) * 12288;                                        \
    gload16(gA0 + kp_, sd_ + wave * 512);                                      \
    gload16(gB0 + kp_, sd_ + 4096 + wave * 1024);                              \
    gload16(gB1 + kp_, sd_ + 4096 + wave * 1024 + 512);                        \
    const uint16_t* rb_ = SH + (RS_) * 12288;                                  \
    _Pragma("unroll") for (int j = 0; j < 4; ++j)                              \
        NB_[j] = *(const bf16x8*)(rb_ + rdB + j * 512);                        \
    _Pragma("unroll") for (int i = 0; i < 4; ++i)                              \
        NA_[i] = *(const bf16x8*)(rb_ + rdA + i * 512);                        \
    __builtin_amdgcn_sched_barrier(0);                                         \
    __builtin_amdgcn_s_setprio(1);                                             \
    _Pragma("unroll") for (int i = 0; i < 4; ++i)                              \
      _Pragma("unroll") for (int j = 0; j < 4; ++j)                            \
          acc[i][j] = __builtin_amdgcn_mfma_f32_16x16x32_bf16(                 \
              CA_[i], CB_[j], acc[i][j], 0, 0, 0);                             \
    __builtin_amdgcn_s_setprio(0);                                             \
    asm volatile("s_waitcnt vmcnt(3)" ::: "memory");                           \
    __builtin_amdgcn_sched_barrier(0);                                         \
    __builtin_amdgcn_s_barrier();                                              \
    __builtin_amdgcn_sched_barrier(0);                                         \
  } while (0)

  for (int t0 = 0; t0 < NT; t0 += 4) {
    PV_T(t0 + 0, 1, 3, fa0, fb0, fa1, fb1);
    PV_T(t0 + 1, 2, 0, fa1, fb1, fa0, fb0);
    PV_T(t0 + 2, 3, 1, fa0, fb0, fa1, fb1);
    PV_T(t0 + 3, 0, 2, fa1, fb1, fa0, fb0);
  }
#undef PV_T

  // drain wrapped tail stages before reusing LDS as the epilogue arena
  asm volatile("s_waitcnt vmcnt(0)" ::: "memory");
  __builtin_amdgcn_sched_barrier(0);
  __builtin_amdgcn_s_barrier();
  __builtin_amdgcn_sched_barrier(0);

  // epilogue: per-wave [16][72] arena bounce, 16B gate loads + stores
  uint16_t* ar = SH + wave * 2048;
  const int lrow = lane >> 3;
  const int nc = (lane & 7) * 8;
#pragma unroll
  for (int i = 0; i < 4; ++i) {
#pragma unroll
    for (int j = 0; j < 4; ++j)
#pragma unroll
      for (int r = 0; r < 4; ++r)
        ar[(rg * 4 + r) * 72 + j * 16 + fr] = f2bf(acc[i][j][r]);
#pragma unroll
    for (int rr = 0; rr < 2; ++rr) {
      const size_t base = (size_t)(m0 + wrM + i * 16 + rr * 8 + lrow) * 2048 + n0 + wcN + nc;
      bf16x8 v = *(const bf16x8*)(ar + (rr * 8 + lrow) * 72 + nc);
      bf16x8 g = *(const bf16x8*)(p.gate + base);
      bf16x8 o;
#pragma unroll
      for (int e = 0; e < 8; ++e) o[e] = (__bf16)((float)v[e] * (float)g[e]);
      *(bf16x8*)(p.o16a + base) = o;
    }
  }
}

// ---------------------------------------------------------------------------
// k_final: y = (out2g@WoT^T + bo) * x, fp32 out. 128x128, K=2048, ring-4.
// ---------------------------------------------------------------------------
__global__ __launch_bounds__(256, 2) void k_final(
    const uint16_t* __restrict__ A,
    const uint16_t* __restrict__ Bt, EpiParams p) {
  __shared__ __align__(16) uint16_t SH[32768];

  const int tid = threadIdx.x;
  const int lane = tid & 63;
  const int wave = tid >> 6;
  const int wr = (wave >> 1) * 64;
  const int wc = (wave & 1) * 64;
  const int m0 = blockIdx.y * 128;
  const int n0 = blockIdx.x * 128;
  const int lda = 2048, ldb = 2048;
  const int NT = 64;   // K=2048

  f32x4 acc[4][4] = {};

  const int fr = lane & 15;
  const int rg = lane >> 4;
  const int swz = (rg ^ ((fr >> 1) & 3)) * 8;
  const int rdA = (wr + fr) * 32 + swz;
  const int rdB = 4096 + (wc + fr) * 32 + swz;

  const int srow = lane >> 2;
  const int sk = ((lane & 3) ^ ((lane >> 3) & 3)) * 8;
  const uint16_t* gA0 = A + (size_t)(m0 + wave * 16 + srow) * lda + sk;
  const uint16_t* gA1 = gA0 + (size_t)64 * lda;
  const uint16_t* gB0 = Bt + (size_t)(n0 + wave * 16 + srow) * ldb + sk;
  const uint16_t* gB1 = gB0 + (size_t)64 * ldb;

  RING_LOOP128();

#pragma unroll
  for (int i = 0; i < 4; ++i) {
#pragma unroll
    for (int j = 0; j < 4; ++j) {
      const int row = m0 + wr + i * 16 + rg * 4;
      const int col = n0 + wc + j * 16 + fr;
      const float bc = p.bias[col];
#pragma unroll
      for (int r = 0; r < 4; ++r) {
        size_t idx = (size_t)(row + r) * 1024 + col;
        p.o32[idx] = (acc[i][j][r] + bc) * p.x[idx];
      }
    }
  }
}

// ---------------- launch ----------------

extern "C" void kernel_launch(void* const* d_in, const int* in_sizes, int n_in,
                              void* d_out, int out_size, void* d_ws, size_t ws_size,
                              hipStream_t stream) {
  const float* x        = (const float*)d_in[0];
  const float* W_hidden = (const float*)d_in[1];
  const float* b_hidden = (const float*)d_in[2];
  const float* W_qk     = (const float*)d_in[3];
  const float* b_qk     = (const float*)d_in[4];
  const float* gamma    = (const float*)d_in[5];
  const float* beta     = (const float*)d_in[6];
  const float* W_out    = (const float*)d_in[7];
  const float* b_out    = (const float*)d_in[8];
  float* out = (float*)d_out;

  const bool fullM = ws_size >= (236ull << 20);
  const size_t region0 = fullM ? (128ull << 20) : (64ull << 20);

  char* base = (char*)d_ws;
  uint16_t* xb    = (uint16_t*)(base);                         // 16 MB  [8192][1024]
  uint16_t* WhT   = (uint16_t*)(base + (16ull << 20));         //  8 MB  [4096][1024]
  uint16_t* WqkT  = (uint16_t*)(base + (24ull << 20));         // .5 MB  [256][1024]
  uint16_t* attnB = (uint16_t*)(base);                         // 64/128 MB
  char* tail = base + region0;
  uint16_t* WoT   = (uint16_t*)(tail);                         //  4 MB  [1024][2048]
  uint16_t* q     = (uint16_t*)(tail + (4ull << 20));          //  4 MB  [8192][256]
  uint16_t* kk    = (uint16_t*)(tail + (8ull << 20));          //  4 MB
  uint16_t* vT    = (uint16_t*)(tail + (12ull << 20));         // 32 MB  [2048][8192]
  uint16_t* gate  = (uint16_t*)(tail + (44ull << 20));         // 32 MB  [8192][2048]
  uint16_t* out2g = (uint16_t*)(tail + (76ull << 20));         // 32 MB  [8192][2048]
  (void)in_sizes; (void)n_in; (void)out_size;

  // prep
  cast_to_bf16<<<(8192 * 1024 / 4) / 256, 256, 0, stream>>>(x, xb, 8192 * 1024 / 4);
  transpose_cast_pad<<<dim3(4096 / 32, 1024 / 32), dim3(32, 8), 0, stream>>>(W_hidden, WhT, 1024, 4096, 4096);
  transpose_cast_pad<<<dim3(256 / 32, 1024 / 32), dim3(32, 8), 0, stream>>>(W_qk, WqkT, 1024, 200, 256);
  transpose_cast_pad<<<dim3(1024 / 32, 2048 / 32), dim3(32, 8), 0, stream>>>(W_out, WoT, 2048, 1024, 1024);

  // fused hid + qk   (N = 4096 + 256 = 4352)
  {
    EpiParams p{};
    p.bias = b_hidden; p.bias2 = b_qk;
    p.g0 = gamma; p.b0 = beta; p.g1 = gamma + 200; p.b1 = beta + 200;
    p.o16a = vT; p.o16b = gate; p.oq = q; p.ok = kk;
    k_hidqk<<<dim3(34, 64), 256, 0, stream>>>(xb, WhT, p);
  }

  if (fullM) {
    k_attn<<<dim3(64, 64), 256, 0, stream>>>(q, kk, attnB);
    {
      EpiParams p{};
      p.gate = gate; p.o16a = out2g;
      k_pv<<<dim3(8 * 64), 512, 0, stream>>>(attnB, 8192, vT, 8192, 8192, 8, p);
    }
  } else {
    for (int s = 0; s < 2; ++s) {
      k_attn<<<dim3(64, 32), 256, 0, stream>>>(q + (size_t)s * 4096 * 256, kk, attnB);
      {
        EpiParams p{};
        p.gate = gate + (size_t)s * 4096 * 2048;
        p.o16a = out2g + (size_t)s * 4096 * 2048;
        k_pv<<<dim3(8 * 32), 512, 0, stream>>>(attnB, 8192, vT, 8192, 8192, 8, p);
      }
    }
  }

  // y = (out2g@Wo + bo) * x
  {
    EpiParams p{};
    p.bias = b_out; p.x = x; p.o32 = out;
    k_final<<<dim3(8, 64), 256, 0, stream>>>(out2g, WoT, p);
  }
}